// Round 1
// baseline (295.340 us; speedup 1.0000x reference)
//
#include <hip/hip_runtime.h>

typedef unsigned short ushort_t;
typedef __attribute__((ext_vector_type(8))) short bf16x8;
typedef __attribute__((ext_vector_type(4))) float f32x4;

#define B_SZ   16
#define NQ     4096
#define NKV    77
#define QDIM   320
#define CDIM   768
#define HEADS  8
#define DHEAD  64
#define INNER  512
#define M_ROWS (B_SZ * NQ)   // 65536

__device__ __forceinline__ ushort_t f2bf(float f) {
  unsigned u = __builtin_bit_cast(unsigned, f);
  u = (u + 0x7fffu + ((u >> 16) & 1u)) >> 16;
  return (ushort_t)u;
}

__device__ __forceinline__ void async16(const ushort_t* g, ushort_t* l) {
  __builtin_amdgcn_global_load_lds(
      (const __attribute__((address_space(1))) unsigned int*)g,
      (__attribute__((address_space(3))) unsigned int*)l,
      16, 0, 0);
}

// ---------------- mask dtype detect + bias table ----------------
// biasT: [16][80] f32, 0 where attended, -1e30 where masked or kv>=77 pad.
__global__ void mask_bias_kernel(const unsigned char* __restrict__ mraw,
                                 float* __restrict__ biasT) {
  __shared__ int s_u8, s_w4;
  if (threadIdx.x == 0) { s_u8 = 0; s_w4 = 0; }
  __syncthreads();
  const int nbytes = B_SZ * NKV;  // 1232 guaranteed bytes
  for (int i = threadIdx.x; i < nbytes; i += blockDim.x) {
    unsigned char v = mraw[i];
    if (v && (i & 3)) atomicOr(&s_u8, 1);          // nonzero off int32 boundary -> u8
    if (v && ((i & 7) == 4)) atomicOr(&s_w4, 1);   // odd-index int32 low byte
  }
  __syncthreads();
  int mode = s_u8 ? 0 : (s_w4 ? 1 : 2);  // 0=u8, 1=i32, 2=i64
  for (int i = threadIdx.x; i < B_SZ * 80; i += blockDim.x) {
    int b = i / 80, kv = i - b * 80;
    float bias = -1e30f;
    if (kv < NKV) {
      int idx = b * NKV + kv;
      long long m;
      if (mode == 0)      m = (long long)mraw[idx];
      else if (mode == 1) m = (long long)((const int*)mraw)[idx];
      else                m = ((const long long*)mraw)[idx];
      bias = m ? 0.0f : -1e30f;
    }
    biasT[i] = bias;
  }
}

// ---------------- casts ----------------
__global__ void cast_f32_bf16(const float* __restrict__ in,
                              ushort_t* __restrict__ out, int n4) {
  int i = blockIdx.x * blockDim.x + threadIdx.x;
  int stride = gridDim.x * blockDim.x;
  const float4* in4 = (const float4*)in;
  ushort4* out4 = (ushort4*)out;
  for (; i < n4; i += stride) {
    float4 v = in4[i];
    ushort4 o;
    o.x = f2bf(v.x); o.y = f2bf(v.y); o.z = f2bf(v.z); o.w = f2bf(v.w);
    out4[i] = o;
  }
}

// out[n][k] = bf16(in[k][n]); rows n>=N zero-filled (pad to Npad rows).
__global__ void tcast_f32_bf16(const float* __restrict__ in,
                               ushort_t* __restrict__ out,
                               int K, int N, int Npad) {
  int i = blockIdx.x * blockDim.x + threadIdx.x;
  int stride = gridDim.x * blockDim.x;
  int total = Npad * K;
  for (; i < total; i += stride) {
    int n = i / K, k = i - n * K;
    out[i] = (n < N) ? f2bf(in[(size_t)k * N + n]) : (ushort_t)0;
  }
}

// ---------------- GEMM: C[M,N] = A[M,K] @ B[K,N], B given transposed [N][K] ----
// 128x128 tile, BK=64, 4 waves (2x2), each wave 64x64 via 4x4 16x16x32 MFMAs.
__global__ __launch_bounds__(256) void gemm_bf16(
    const ushort_t* __restrict__ A, const ushort_t* __restrict__ Bt,
    ushort_t* __restrict__ Cb, float* __restrict__ Cf,
    const float* __restrict__ bias,
    int K, int Astride, int Bstride, int Cstride, int Nvalid) {
  __shared__ ushort_t As[128 * 64];
  __shared__ ushort_t Bs[128 * 64];
  const int tid = threadIdx.x;
  const int wid = tid >> 6, lane = tid & 63;
  const int wr = wid >> 1, wc = wid & 1;
  const int tileM = blockIdx.x * 128, tileN = blockIdx.y * 128;

  f32x4 acc[4][4];
#pragma unroll
  for (int m = 0; m < 4; ++m)
#pragma unroll
    for (int n = 0; n < 4; ++n) acc[m][n] = (f32x4){0.f, 0.f, 0.f, 0.f};

  const int srow = lane >> 3;        // 0..7
  const int scol = (lane & 7) * 8;   // 0..56

  for (int kt = 0; kt < K; kt += 64) {
    __syncthreads();
#pragma unroll
    for (int j = 0; j < 4; ++j) {
      int s = wid * 4 + j;  // 16 slots of 8 rows
      const ushort_t* ga = A + (size_t)(tileM + s * 8 + srow) * Astride + kt + scol;
      const ushort_t* gb = Bt + (size_t)(tileN + s * 8 + srow) * Bstride + kt + scol;
      async16(ga, As + s * 512);
      async16(gb, Bs + s * 512);
    }
    __syncthreads();
#pragma unroll
    for (int kc = 0; kc < 2; ++kc) {
      bf16x8 af[4], bfr[4];
#pragma unroll
      for (int m = 0; m < 4; ++m)
        af[m] = *(const bf16x8*)&As[(wr * 64 + m * 16 + (lane & 15)) * 64 + kc * 32 + (lane >> 4) * 8];
#pragma unroll
      for (int n = 0; n < 4; ++n)
        bfr[n] = *(const bf16x8*)&Bs[(wc * 64 + n * 16 + (lane & 15)) * 64 + kc * 32 + (lane >> 4) * 8];
#pragma unroll
      for (int m = 0; m < 4; ++m)
#pragma unroll
        for (int n = 0; n < 4; ++n)
          acc[m][n] = __builtin_amdgcn_mfma_f32_16x16x32_bf16(af[m], bfr[n], acc[m][n], 0, 0, 0);
    }
  }

  const int r0 = tileM + wr * 64;
  const int c0 = tileN + wc * 64;
  const int rl = (lane >> 4) * 4;
  const int cl = lane & 15;
  if (Cf) {
#pragma unroll
    for (int m = 0; m < 4; ++m)
#pragma unroll
      for (int n = 0; n < 4; ++n) {
        int col = c0 + n * 16 + cl;
        if (col < Nvalid) {
          float bv = bias ? bias[col] : 0.f;
#pragma unroll
          for (int r = 0; r < 4; ++r)
            Cf[(size_t)(r0 + m * 16 + rl + r) * Cstride + col] = acc[m][n][r] + bv;
        }
      }
  } else {
#pragma unroll
    for (int m = 0; m < 4; ++m)
#pragma unroll
      for (int n = 0; n < 4; ++n) {
        int col = c0 + n * 16 + cl;
#pragma unroll
        for (int r = 0; r < 4; ++r)
          Cb[(size_t)(r0 + m * 16 + rl + r) * Cstride + col] = f2bf(acc[m][n][r]);
      }
  }
}

// ---------------- fused attention (per block: one b, one head, 64 q-rows) ----
__global__ __launch_bounds__(256) void attn_kernel(
    const ushort_t* __restrict__ qb, const ushort_t* __restrict__ kb,
    const ushort_t* __restrict__ vb, const float* __restrict__ biasT,
    ushort_t* __restrict__ ab) {
  __shared__ ushort_t Vt[64 * 96];      // [d][kv], kv padded to 96
  __shared__ ushort_t P[4][16 * 96];    // per-wave probs [row][kv]
  const int qt = blockIdx.x, h = blockIdx.y, b = blockIdx.z;
  const int tid = threadIdx.x, wid = tid >> 6, lane = tid & 63;
  const int rl = lane & 15;
  const int kh = (lane >> 4) * 8;

  // phase 1: stage V transposed + zero P
  for (int i = tid; i < 96 * 64; i += 256) {
    int kv = i >> 6, d = i & 63;
    ushort_t v = (kv < NKV) ? vb[(size_t)(b * NKV + kv) * INNER + h * 64 + d] : (ushort_t)0;
    Vt[d * 96 + kv] = v;
  }
  for (int i = tid; i < 4 * 16 * 96; i += 256) (&P[0][0])[i] = 0;

  // Q fragments (direct 16B global loads)
  const size_t qrow = (size_t)(b * NQ + qt * 64 + wid * 16 + rl);
  bf16x8 qf[2];
#pragma unroll
  for (int kc = 0; kc < 2; ++kc)
    qf[kc] = *(const bf16x8*)&qb[qrow * INNER + h * 64 + kc * 32 + kh];

  __syncthreads();

  // phase 2: QK^T -> scale+bias -> softmax -> P (unnormalized, bf16)
  f32x4 s[5];
#pragma unroll
  for (int nt = 0; nt < 5; ++nt) {
    s[nt] = (f32x4){0.f, 0.f, 0.f, 0.f};
    int kv = nt * 16 + rl;
    bf16x8 kf0 = {0, 0, 0, 0, 0, 0, 0, 0};
    bf16x8 kf1 = {0, 0, 0, 0, 0, 0, 0, 0};
    if (kv < NKV) {
      const ushort_t* kp = &kb[(size_t)(b * NKV + kv) * INNER + h * 64 + kh];
      kf0 = *(const bf16x8*)(kp);
      kf1 = *(const bf16x8*)(kp + 32);
    }
    s[nt] = __builtin_amdgcn_mfma_f32_16x16x32_bf16(qf[0], kf0, s[nt], 0, 0, 0);
    s[nt] = __builtin_amdgcn_mfma_f32_16x16x32_bf16(qf[1], kf1, s[nt], 0, 0, 0);
  }

  float bias_v[5];
#pragma unroll
  for (int nt = 0; nt < 5; ++nt) bias_v[nt] = biasT[b * 80 + nt * 16 + rl];

  float mx[4] = {-3.0e38f, -3.0e38f, -3.0e38f, -3.0e38f};
#pragma unroll
  for (int nt = 0; nt < 5; ++nt)
#pragma unroll
    for (int r = 0; r < 4; ++r) {
      float v = s[nt][r] * 0.125f + bias_v[nt];
      s[nt][r] = v;
      mx[r] = fmaxf(mx[r], v);
    }
#pragma unroll
  for (int d = 1; d < 16; d <<= 1)
#pragma unroll
    for (int r = 0; r < 4; ++r) mx[r] = fmaxf(mx[r], __shfl_xor(mx[r], d, 64));

  float sm[4] = {0.f, 0.f, 0.f, 0.f};
#pragma unroll
  for (int nt = 0; nt < 5; ++nt)
#pragma unroll
    for (int r = 0; r < 4; ++r) {
      float p = __expf(s[nt][r] - mx[r]);
      s[nt][r] = p;
      sm[r] += p;
    }
#pragma unroll
  for (int d = 1; d < 16; d <<= 1)
#pragma unroll
    for (int r = 0; r < 4; ++r) sm[r] += __shfl_xor(sm[r], d, 64);

  float rcp[4];
#pragma unroll
  for (int r = 0; r < 4; ++r) rcp[r] = 1.0f / sm[r];

#pragma unroll
  for (int nt = 0; nt < 5; ++nt)
#pragma unroll
    for (int r = 0; r < 4; ++r)
      P[wid][((lane >> 4) * 4 + r) * 96 + nt * 16 + rl] = f2bf(s[nt][r]);

  __syncthreads();

  // phase 3: PV
  f32x4 o[4];
#pragma unroll
  for (int n = 0; n < 4; ++n) o[n] = (f32x4){0.f, 0.f, 0.f, 0.f};
#pragma unroll
  for (int kc = 0; kc < 3; ++kc) {
    bf16x8 pf = *(const bf16x8*)&P[wid][rl * 96 + kc * 32 + kh];
#pragma unroll
    for (int n = 0; n < 4; ++n) {
      bf16x8 vf = *(const bf16x8*)&Vt[(n * 16 + rl) * 96 + kc * 32 + kh];
      o[n] = __builtin_amdgcn_mfma_f32_16x16x32_bf16(pf, vf, o[n], 0, 0, 0);
    }
  }

#pragma unroll
  for (int n = 0; n < 4; ++n)
#pragma unroll
    for (int r = 0; r < 4; ++r) {
      size_t orow = (size_t)(b * NQ + qt * 64 + wid * 16 + (lane >> 4) * 4 + r);
      ab[orow * INNER + h * 64 + n * 16 + rl] = f2bf(o[n][r] * rcp[r]);
    }
}

// ---------------- host ----------------
extern "C" void kernel_launch(void* const* d_in, const int* in_sizes, int n_in,
                              void* d_out, int out_size, void* d_ws, size_t ws_size,
                              hipStream_t stream) {
  (void)in_sizes; (void)n_in; (void)out_size; (void)ws_size;
  const float* x   = (const float*)d_in[0];
  const float* ctx = (const float*)d_in[1];
  const unsigned char* mask = (const unsigned char*)d_in[2];
  const float* Wq = (const float*)d_in[3];
  const float* Wk = (const float*)d_in[4];
  const float* Wv = (const float*)d_in[5];
  const float* Wo = (const float*)d_in[6];
  const float* bo = (const float*)d_in[7];
  float* out = (float*)d_out;

  char* ws = (char*)d_ws;
  size_t off = 0;
  auto alloc = [&](size_t bytes) {
    char* p = ws + off;
    off += (bytes + 255) & ~(size_t)255;
    return p;
  };
  float*    biasT   = (float*)alloc(B_SZ * 80 * sizeof(float));
  ushort_t* region1 = (ushort_t*)alloc((size_t)M_ROWS * INNER * 2);  // xb & ab share
  ushort_t* xb = region1;                  // [65536][320]
  ushort_t* ab = region1;                  // [65536][512] (after xb is dead)
  ushort_t* qb  = (ushort_t*)alloc((size_t)M_ROWS * INNER * 2);      // [65536][512]
  ushort_t* cb  = (ushort_t*)alloc((size_t)1280 * CDIM * 2);         // ctx bf16, M padded
  ushort_t* Wqb = (ushort_t*)alloc((size_t)INNER * QDIM * 2);        // [512][320] = Wq^T
  ushort_t* Wkb = (ushort_t*)alloc((size_t)INNER * CDIM * 2);        // [512][768] = Wk^T
  ushort_t* Wvb = (ushort_t*)alloc((size_t)INNER * CDIM * 2);        // [512][768] = Wv^T
  ushort_t* Wob = (ushort_t*)alloc((size_t)384 * INNER * 2);         // [384][512] = Wo^T pad
  ushort_t* kb  = (ushort_t*)alloc((size_t)1280 * INNER * 2);
  ushort_t* vb  = (ushort_t*)alloc((size_t)1280 * INNER * 2);

  mask_bias_kernel<<<1, 256, 0, stream>>>(mask, biasT);
  cast_f32_bf16<<<2048, 256, 0, stream>>>(x, xb, M_ROWS * QDIM / 4);
  cast_f32_bf16<<<512, 256, 0, stream>>>(ctx, cb, B_SZ * NKV * CDIM / 4);
  tcast_f32_bf16<<<640, 256, 0, stream>>>(Wq, Wqb, QDIM, INNER, INNER);
  tcast_f32_bf16<<<1536, 256, 0, stream>>>(Wk, Wkb, CDIM, INNER, INNER);
  tcast_f32_bf16<<<1536, 256, 0, stream>>>(Wv, Wvb, CDIM, INNER, INNER);
  tcast_f32_bf16<<<768, 256, 0, stream>>>(Wo, Wob, INNER, QDIM, 384);

  // q = x @ Wq
  dim3 g1(M_ROWS / 128, INNER / 128);
  gemm_bf16<<<g1, 256, 0, stream>>>(xb, Wqb, qb, nullptr, nullptr,
                                    QDIM, QDIM, QDIM, INNER, INNER);
  // k,v = ctx @ Wk / Wv  (M padded 1232->1280; pad rows produce unread garbage)
  dim3 g2(1280 / 128, INNER / 128);
  gemm_bf16<<<g2, 256, 0, stream>>>(cb, Wkb, kb, nullptr, nullptr,
                                    CDIM, CDIM, CDIM, INNER, INNER);
  gemm_bf16<<<g2, 256, 0, stream>>>(cb, Wvb, vb, nullptr, nullptr,
                                    CDIM, CDIM, CDIM, INNER, INNER);
  // attention
  dim3 ga(NQ / 64, HEADS, B_SZ);
  attn_kernel<<<ga, 256, 0, stream>>>(qb, kb, vb, biasT, ab);
  // out = a @ Wo + bo  (N padded 320->384, stores predicated)
  dim3 g3(M_ROWS / 128, 384 / 128);
  gemm_bf16<<<g3, 256, 0, stream>>>(ab, Wob, nullptr, out, bo,
                                    INNER, INNER, INNER, QDIM, QDIM);
}

// Round 2
// 223.800 us; speedup vs baseline: 1.3197x; 1.3197x over previous
//
#include <hip/hip_runtime.h>

typedef unsigned short ushort_t;
typedef __attribute__((ext_vector_type(8))) short bf16x8;
typedef __attribute__((ext_vector_type(4))) float f32x4;

#define B_SZ   16
#define NQ     4096
#define NKV    77
#define QDIM   320
#define CDIM   768
#define HEADS  8
#define DHEAD  64
#define INNER  512
#define M_ROWS (B_SZ * NQ)   // 65536
#define VT_STR 104           // padded kv stride: 208B -> 8-bank cycle, 2-way (free)

__device__ __forceinline__ ushort_t f2bf(float f) {
  unsigned u = __builtin_bit_cast(unsigned, f);
  u = (u + 0x7fffu + ((u >> 16) & 1u)) >> 16;
  return (ushort_t)u;
}

__device__ __forceinline__ void async16(const ushort_t* g, ushort_t* l) {
  __builtin_amdgcn_global_load_lds(
      (const __attribute__((address_space(1))) unsigned int*)g,
      (__attribute__((address_space(3))) unsigned int*)l,
      16, 0, 0);
}

// ---------------- mask dtype detect + bias table ----------------
// biasT: [16][80] f32: 0 attended, -1e30 masked, -2e30 kv>=77 pad.
// (-2e30 pad stays exactly-0 after exp even in the all-masked edge case.)
__global__ void mask_bias_kernel(const unsigned char* __restrict__ mraw,
                                 float* __restrict__ biasT) {
  __shared__ int s_u8, s_w4;
  if (threadIdx.x == 0) { s_u8 = 0; s_w4 = 0; }
  __syncthreads();
  const int nbytes = B_SZ * NKV;  // 1232 guaranteed bytes
  for (int i = threadIdx.x; i < nbytes; i += blockDim.x) {
    unsigned char v = mraw[i];
    if (v && (i & 3)) atomicOr(&s_u8, 1);
    if (v && ((i & 7) == 4)) atomicOr(&s_w4, 1);
  }
  __syncthreads();
  int mode = s_u8 ? 0 : (s_w4 ? 1 : 2);  // 0=u8, 1=i32, 2=i64
  for (int i = threadIdx.x; i < B_SZ * 80; i += blockDim.x) {
    int b = i / 80, kv = i - b * 80;
    float bias = -2e30f;
    if (kv < NKV) {
      int idx = b * NKV + kv;
      long long m;
      if (mode == 0)      m = (long long)mraw[idx];
      else if (mode == 1) m = (long long)((const int*)mraw)[idx];
      else                m = ((const long long*)mraw)[idx];
      bias = m ? 0.0f : -1e30f;
    }
    biasT[i] = bias;
  }
}

// ---------------- casts ----------------
__global__ void cast_f32_bf16(const float* __restrict__ in,
                              ushort_t* __restrict__ out, int n4) {
  int i = blockIdx.x * blockDim.x + threadIdx.x;
  int stride = gridDim.x * blockDim.x;
  const float4* in4 = (const float4*)in;
  ushort4* out4 = (ushort4*)out;
  for (; i < n4; i += stride) {
    float4 v = in4[i];
    ushort4 o;
    o.x = f2bf(v.x); o.y = f2bf(v.y); o.z = f2bf(v.z); o.w = f2bf(v.w);
    out4[i] = o;
  }
}

// out[n][k] = bf16(in[k][n] * scale); rows n>=N zero-filled.
__global__ void tcast_f32_bf16(const float* __restrict__ in,
                               ushort_t* __restrict__ out,
                               int K, int N, int Npad, float scale) {
  int i = blockIdx.x * blockDim.x + threadIdx.x;
  int stride = gridDim.x * blockDim.x;
  int total = Npad * K;
  for (; i < total; i += stride) {
    int n = i / K, k = i - n * K;
    out[i] = (n < N) ? f2bf(in[(size_t)k * N + n] * scale) : (ushort_t)0;
  }
}

// vt[b][h][d][kv(104 pad)] = V[b][kv][h*64+d]; kv>=77 -> 0.
// V lives in kvb cols 512..1023.
__global__ void vtrans_kernel(const ushort_t* __restrict__ kvb,
                              ushort_t* __restrict__ vt) {
  const int h = blockIdx.y, b = blockIdx.z;
  const int wid = threadIdx.x >> 6, lane = threadIdx.x & 63;
  const int d = blockIdx.x * 4 + wid;
  ushort_t* dst = vt + (size_t)(b * HEADS + h) * (64 * VT_STR) + d * VT_STR;
  for (int kv = lane; kv < VT_STR; kv += 64)
    dst[kv] = (kv < NKV)
        ? kvb[(size_t)(b * NKV + kv) * 1024 + 512 + h * 64 + d]
        : (ushort_t)0;
}

// ---------------- GEMM: C[M,N] = A[M,K] @ B[K,N], B given transposed [N][K] ----
__global__ __launch_bounds__(256) void gemm_bf16(
    const ushort_t* __restrict__ A, const ushort_t* __restrict__ Bt,
    ushort_t* __restrict__ Cb, float* __restrict__ Cf,
    const float* __restrict__ bias,
    int K, int Astride, int Bstride, int Cstride, int Nvalid) {
  __shared__ ushort_t As[128 * 64];
  __shared__ ushort_t Bs[128 * 64];
  const int tid = threadIdx.x;
  const int wid = tid >> 6, lane = tid & 63;
  const int wr = wid >> 1, wc = wid & 1;
  const int tileM = blockIdx.x * 128, tileN = blockIdx.y * 128;

  f32x4 acc[4][4];
#pragma unroll
  for (int m = 0; m < 4; ++m)
#pragma unroll
    for (int n = 0; n < 4; ++n) acc[m][n] = (f32x4){0.f, 0.f, 0.f, 0.f};

  const int srow = lane >> 3;        // 0..7
  const int scol = (lane & 7) * 8;   // 0..56

  for (int kt = 0; kt < K; kt += 64) {
    __syncthreads();
#pragma unroll
    for (int j = 0; j < 4; ++j) {
      int s = wid * 4 + j;
      const ushort_t* ga = A + (size_t)(tileM + s * 8 + srow) * Astride + kt + scol;
      const ushort_t* gb = Bt + (size_t)(tileN + s * 8 + srow) * Bstride + kt + scol;
      async16(ga, As + s * 512);
      async16(gb, Bs + s * 512);
    }
    __syncthreads();
#pragma unroll
    for (int kc = 0; kc < 2; ++kc) {
      bf16x8 af[4], bfr[4];
#pragma unroll
      for (int m = 0; m < 4; ++m)
        af[m] = *(const bf16x8*)&As[(wr * 64 + m * 16 + (lane & 15)) * 64 + kc * 32 + (lane >> 4) * 8];
#pragma unroll
      for (int n = 0; n < 4; ++n)
        bfr[n] = *(const bf16x8*)&Bs[(wc * 64 + n * 16 + (lane & 15)) * 64 + kc * 32 + (lane >> 4) * 8];
#pragma unroll
      for (int m = 0; m < 4; ++m)
#pragma unroll
        for (int n = 0; n < 4; ++n)
          acc[m][n] = __builtin_amdgcn_mfma_f32_16x16x32_bf16(af[m], bfr[n], acc[m][n], 0, 0, 0);
    }
  }

  const int r0 = tileM + wr * 64;
  const int c0 = tileN + wc * 64;
  const int rl2 = (lane >> 4) * 4;
  const int cl = lane & 15;
  if (Cf) {
#pragma unroll
    for (int m = 0; m < 4; ++m)
#pragma unroll
      for (int n = 0; n < 4; ++n) {
        int col = c0 + n * 16 + cl;
        if (col < Nvalid) {
          float bv = bias ? bias[col] : 0.f;
#pragma unroll
          for (int r = 0; r < 4; ++r)
            Cf[(size_t)(r0 + m * 16 + rl2 + r) * Cstride + col] = acc[m][n][r] + bv;
        }
      }
  } else {
#pragma unroll
    for (int m = 0; m < 4; ++m)
#pragma unroll
      for (int n = 0; n < 4; ++n) {
        int col = c0 + n * 16 + cl;
#pragma unroll
        for (int r = 0; r < 4; ++r)
          Cb[(size_t)(r0 + m * 16 + rl2 + r) * Cstride + col] = f2bf(acc[m][n][r]);
      }
  }
}

// ---------------- fused attention ----------------
// block = (qt: 256 rows, h, b); 4 waves; 4 chunks of 64 rows (16 rows/wave).
// Vt staged via async16 from pre-transposed vt (conflict-free stride 104).
// K fragments + bias hoisted (loaded once per block, reused 4 chunks).
__global__ __launch_bounds__(256) void attn_kernel(
    const ushort_t* __restrict__ qb, const ushort_t* __restrict__ kvb,
    const ushort_t* __restrict__ vt, const float* __restrict__ biasT,
    ushort_t* __restrict__ ab) {
  __shared__ ushort_t Vt[64 * VT_STR];       // 13312 B
  __shared__ ushort_t P[4 * 16 * VT_STR];    // 13312 B (per-wave 16x104)
  const int qt = blockIdx.x, h = blockIdx.y, b = blockIdx.z;
  const int tid = threadIdx.x, wid = tid >> 6, lane = tid & 63;
  const int rl = lane & 15;
  const int kh = (lane >> 4) * 8;

  // stage Vt (832 x 16B, contiguous; last iter = wave 0 only -> uniform)
  const ushort_t* vtg = vt + (size_t)(b * HEADS + h) * (64 * VT_STR);
  for (int i = tid; i < 832; i += 256) async16(vtg + i * 8, Vt + i * 8);
  // zero P (cols 80..103 stay zero forever -> PV pad-k reads are exact 0)
  for (int i = tid; i < 832; i += 256)
    *(bf16x8*)&P[i * 8] = (bf16x8){0, 0, 0, 0, 0, 0, 0, 0};

  // hoisted K fragments + bias
  bf16x8 kf[5][2];
  float bias_v[5];
#pragma unroll
  for (int nt = 0; nt < 5; ++nt) {
    int kv = nt * 16 + rl;
    bias_v[nt] = biasT[b * 80 + kv];
    kf[nt][0] = (bf16x8){0, 0, 0, 0, 0, 0, 0, 0};
    kf[nt][1] = (bf16x8){0, 0, 0, 0, 0, 0, 0, 0};
    if (kv < NKV) {
      const ushort_t* kp = &kvb[(size_t)(b * NKV + kv) * 1024 + h * 64 + kh];
      kf[nt][0] = *(const bf16x8*)kp;
      kf[nt][1] = *(const bf16x8*)(kp + 32);
    }
  }
  __syncthreads();

  const int qbase = b * NQ + qt * 256;
  const int pbase = wid * (16 * VT_STR);
#pragma unroll 1
  for (int chunk = 0; chunk < 4; ++chunk) {
    if (chunk) __syncthreads();  // prev chunk's O readers done before P rewrite
    const int row0 = chunk * 64 + wid * 16;

    // Q fragments (scale pre-folded into Wq)
    const ushort_t* qp = &qb[(size_t)(qbase + row0 + rl) * INNER + h * 64 + kh];
    bf16x8 qf0 = *(const bf16x8*)qp;
    bf16x8 qf1 = *(const bf16x8*)(qp + 32);

    // QK^T
    f32x4 s[5];
#pragma unroll
    for (int nt = 0; nt < 5; ++nt) {
      s[nt] = (f32x4){0.f, 0.f, 0.f, 0.f};
      s[nt] = __builtin_amdgcn_mfma_f32_16x16x32_bf16(qf0, kf[nt][0], s[nt], 0, 0, 0);
      s[nt] = __builtin_amdgcn_mfma_f32_16x16x32_bf16(qf1, kf[nt][1], s[nt], 0, 0, 0);
    }

    // softmax (rows = (lane>>4)*4+r, cols = 16-lane groups)
    float mx[4] = {-3.0e38f, -3.0e38f, -3.0e38f, -3.0e38f};
#pragma unroll
    for (int nt = 0; nt < 5; ++nt)
#pragma unroll
      for (int r = 0; r < 4; ++r) {
        float v = s[nt][r] + bias_v[nt];
        s[nt][r] = v;
        mx[r] = fmaxf(mx[r], v);
      }
#pragma unroll
    for (int d = 1; d < 16; d <<= 1)
#pragma unroll
      for (int r = 0; r < 4; ++r) mx[r] = fmaxf(mx[r], __shfl_xor(mx[r], d, 64));

    float sm[4] = {0.f, 0.f, 0.f, 0.f};
#pragma unroll
    for (int nt = 0; nt < 5; ++nt)
#pragma unroll
      for (int r = 0; r < 4; ++r) {
        float p = __expf(s[nt][r] - mx[r]);
        s[nt][r] = p;
        sm[r] += p;
      }
#pragma unroll
    for (int d = 1; d < 16; d <<= 1)
#pragma unroll
      for (int r = 0; r < 4; ++r) sm[r] += __shfl_xor(sm[r], d, 64);

    float rcp[4];
#pragma unroll
    for (int r = 0; r < 4; ++r) rcp[r] = 1.0f / sm[r];

    // P (unnormalized bf16) -> LDS, stride 104
#pragma unroll
    for (int nt = 0; nt < 5; ++nt)
#pragma unroll
      for (int r = 0; r < 4; ++r)
        P[pbase + ((lane >> 4) * 4 + r) * VT_STR + nt * 16 + rl] = f2bf(s[nt][r]);

    // PV (wave-local P + shared Vt; both conflict-free)
    f32x4 o[4];
#pragma unroll
    for (int n = 0; n < 4; ++n) o[n] = (f32x4){0.f, 0.f, 0.f, 0.f};
#pragma unroll
    for (int kc = 0; kc < 3; ++kc) {
      bf16x8 pf = *(const bf16x8*)&P[pbase + rl * VT_STR + kc * 32 + kh];
#pragma unroll
      for (int n = 0; n < 4; ++n) {
        bf16x8 vf = *(const bf16x8*)&Vt[(n * 16 + rl) * VT_STR + kc * 32 + kh];
        o[n] = __builtin_amdgcn_mfma_f32_16x16x32_bf16(pf, vf, o[n], 0, 0, 0);
      }
    }

    // normalized O back into P[wid] cols 0..63 (after pf reads; wave-private)
#pragma unroll
    for (int n = 0; n < 4; ++n)
#pragma unroll
      for (int r = 0; r < 4; ++r)
        P[pbase + ((lane >> 4) * 4 + r) * VT_STR + n * 16 + rl] = f2bf(o[n][r] * rcp[r]);

    __syncthreads();

    // coalesced O write: 32B/thread, 4 threads span one 128B row slice
    {
      const int rflat = tid >> 2, d0 = (tid & 3) * 16;
      const ushort_t* src = &P[(rflat >> 4) * (16 * VT_STR) + (rflat & 15) * VT_STR + d0];
      ushort_t* dst = &ab[(size_t)(qbase + chunk * 64 + rflat) * INNER + h * 64 + d0];
      *(bf16x8*)dst = *(const bf16x8*)src;
      *(bf16x8*)(dst + 8) = *(const bf16x8*)(src + 8);
    }
  }
}

// ---------------- host ----------------
extern "C" void kernel_launch(void* const* d_in, const int* in_sizes, int n_in,
                              void* d_out, int out_size, void* d_ws, size_t ws_size,
                              hipStream_t stream) {
  (void)in_sizes; (void)n_in; (void)out_size; (void)ws_size;
  const float* x   = (const float*)d_in[0];
  const float* ctx = (const float*)d_in[1];
  const unsigned char* mask = (const unsigned char*)d_in[2];
  const float* Wq = (const float*)d_in[3];
  const float* Wk = (const float*)d_in[4];
  const float* Wv = (const float*)d_in[5];
  const float* Wo = (const float*)d_in[6];
  const float* bo = (const float*)d_in[7];
  float* out = (float*)d_out;

  char* ws = (char*)d_ws;
  size_t off = 0;
  auto alloc = [&](size_t bytes) {
    char* p = ws + off;
    off += (bytes + 255) & ~(size_t)255;
    return p;
  };
  float*    biasT   = (float*)alloc(B_SZ * 80 * sizeof(float));
  ushort_t* region1 = (ushort_t*)alloc((size_t)M_ROWS * INNER * 2);  // xb & ab share
  ushort_t* xb = region1;                   // [65536][320]
  ushort_t* ab = region1;                   // [65536][512] (xb dead by then)
  ushort_t* qb   = (ushort_t*)alloc((size_t)M_ROWS * INNER * 2);     // [65536][512]
  ushort_t* cb   = (ushort_t*)alloc((size_t)1280 * CDIM * 2);        // ctx bf16 padded
  ushort_t* Wqb  = (ushort_t*)alloc((size_t)INNER * QDIM * 2);       // [512][320] = (0.125*Wq)^T
  ushort_t* Wkvb = (ushort_t*)alloc((size_t)1024 * CDIM * 2);        // [[Wk^T];[Wv^T]]
  ushort_t* Wob  = (ushort_t*)alloc((size_t)384 * INNER * 2);        // [384][512] = Wo^T pad
  ushort_t* kvb  = (ushort_t*)alloc((size_t)1280 * 1024 * 2);        // [1280][1024]
  ushort_t* vt   = (ushort_t*)alloc((size_t)B_SZ * HEADS * 64 * VT_STR * 2);

  mask_bias_kernel<<<1, 256, 0, stream>>>(mask, biasT);
  cast_f32_bf16<<<2048, 256, 0, stream>>>(x, xb, M_ROWS * QDIM / 4);
  cast_f32_bf16<<<512, 256, 0, stream>>>(ctx, cb, B_SZ * NKV * CDIM / 4);
  tcast_f32_bf16<<<640, 256, 0, stream>>>(Wq, Wqb, QDIM, INNER, INNER, 0.125f);
  tcast_f32_bf16<<<1536, 256, 0, stream>>>(Wk, Wkvb, CDIM, INNER, INNER, 1.0f);
  tcast_f32_bf16<<<1536, 256, 0, stream>>>(Wv, Wkvb + (size_t)INNER * CDIM, CDIM, INNER, INNER, 1.0f);
  tcast_f32_bf16<<<768, 256, 0, stream>>>(Wo, Wob, INNER, QDIM, 384, 1.0f);

  // q = x @ (0.125*Wq)
  dim3 g1(M_ROWS / 128, INNER / 128);
  gemm_bf16<<<g1, 256, 0, stream>>>(xb, Wqb, qb, nullptr, nullptr,
                                    QDIM, QDIM, QDIM, INNER, INNER);
  // [k|v] = ctx @ [Wk|Wv]  (one GEMM, N=1024)
  dim3 g2(1280 / 128, 1024 / 128);
  gemm_bf16<<<g2, 256, 0, stream>>>(cb, Wkvb, kvb, nullptr, nullptr,
                                    CDIM, CDIM, CDIM, 1024, 1024);
  // V -> vt[b][h][d][104] (zero-padded, conflict-free stride)
  vtrans_kernel<<<dim3(16, HEADS, B_SZ), 256, 0, stream>>>(kvb, vt);
  // attention
  attn_kernel<<<dim3(NQ / 256, HEADS, B_SZ), 256, 0, stream>>>(qb, kvb, vt, biasT, ab);
  // out = a @ Wo + bo
  dim3 g3(M_ROWS / 128, 384 / 128);
  gemm_bf16<<<g3, 256, 0, stream>>>(ab, Wob, nullptr, out, bo,
                                    INNER, INNER, INNER, QDIM, QDIM);
}

// Round 3
// 191.920 us; speedup vs baseline: 1.5389x; 1.1661x over previous
//
#include <hip/hip_runtime.h>

typedef unsigned short ushort_t;
typedef __attribute__((ext_vector_type(8))) short bf16x8;
typedef __attribute__((ext_vector_type(4))) float f32x4;

#define B_SZ   16
#define NQ     4096
#define NKV    77
#define QDIM   320
#define CDIM   768
#define HEADS  8
#define DHEAD  64
#define INNER  512
#define M_ROWS (B_SZ * NQ)   // 65536
#define VT_STR 104           // padded kv stride: 208B -> 8-bank cycle, 2-way (free)

__device__ __forceinline__ ushort_t f2bf(float f) {
  unsigned u = __builtin_bit_cast(unsigned, f);
  u = (u + 0x7fffu + ((u >> 16) & 1u)) >> 16;
  return (ushort_t)u;
}

__device__ __forceinline__ void async16(const ushort_t* g, ushort_t* l) {
  __builtin_amdgcn_global_load_lds(
      (const __attribute__((address_space(1))) unsigned int*)g,
      (__attribute__((address_space(3))) unsigned int*)l,
      16, 0, 0);
}

// ---------------- mask dtype detect + bias table ----------------
__global__ void mask_bias_kernel(const unsigned char* __restrict__ mraw,
                                 float* __restrict__ biasT) {
  __shared__ int s_u8, s_w4;
  if (threadIdx.x == 0) { s_u8 = 0; s_w4 = 0; }
  __syncthreads();
  const int nbytes = B_SZ * NKV;  // 1232 guaranteed bytes
  for (int i = threadIdx.x; i < nbytes; i += blockDim.x) {
    unsigned char v = mraw[i];
    if (v && (i & 3)) atomicOr(&s_u8, 1);
    if (v && ((i & 7) == 4)) atomicOr(&s_w4, 1);
  }
  __syncthreads();
  int mode = s_u8 ? 0 : (s_w4 ? 1 : 2);  // 0=u8, 1=i32, 2=i64
  for (int i = threadIdx.x; i < B_SZ * 80; i += blockDim.x) {
    int b = i / 80, kv = i - b * 80;
    float bias = -2e30f;
    if (kv < NKV) {
      int idx = b * NKV + kv;
      long long m;
      if (mode == 0)      m = (long long)mraw[idx];
      else if (mode == 1) m = (long long)((const int*)mraw)[idx];
      else                m = ((const long long*)mraw)[idx];
      bias = m ? 0.0f : -1e30f;
    }
    biasT[i] = bias;
  }
}

// ---------------- casts ----------------
__global__ void cast_f32_bf16(const float* __restrict__ in,
                              ushort_t* __restrict__ out, int n4) {
  int i = blockIdx.x * blockDim.x + threadIdx.x;
  int stride = gridDim.x * blockDim.x;
  const float4* in4 = (const float4*)in;
  ushort4* out4 = (ushort4*)out;
  for (; i < n4; i += stride) {
    float4 v = in4[i];
    ushort4 o;
    o.x = f2bf(v.x); o.y = f2bf(v.y); o.z = f2bf(v.z); o.w = f2bf(v.w);
    out4[i] = o;
  }
}

// out[n][k] = bf16(in[k][n] * scale); rows n>=N zero-filled.
__global__ void tcast_f32_bf16(const float* __restrict__ in,
                               ushort_t* __restrict__ out,
                               int K, int N, int Npad, float scale) {
  int i = blockIdx.x * blockDim.x + threadIdx.x;
  int stride = gridDim.x * blockDim.x;
  int total = Npad * K;
  for (; i < total; i += stride) {
    int n = i / K, k = i - n * K;
    out[i] = (n < N) ? f2bf(in[(size_t)k * N + n] * scale) : (ushort_t)0;
  }
}

// vt[b][h][d][kv(104 pad)] = V[b][kv][h*64+d]; kv>=77 -> 0.
__global__ void vtrans_kernel(const ushort_t* __restrict__ kvb,
                              ushort_t* __restrict__ vt) {
  const int h = blockIdx.y, b = blockIdx.z;
  const int wid = threadIdx.x >> 6, lane = threadIdx.x & 63;
  const int d = blockIdx.x * 4 + wid;
  ushort_t* dst = vt + (size_t)(b * HEADS + h) * (64 * VT_STR) + d * VT_STR;
  for (int kv = lane; kv < VT_STR; kv += 64)
    dst[kv] = (kv < NKV)
        ? kvb[(size_t)(b * NKV + kv) * 1024 + 512 + h * 64 + d]
        : (ushort_t)0;
}

// ---------------- generic 128x128 GEMM (kept for the small kv projection) ----
__global__ __launch_bounds__(256) void gemm_bf16(
    const ushort_t* __restrict__ A, const ushort_t* __restrict__ Bt,
    ushort_t* __restrict__ Cb,
    int K, int Astride, int Bstride, int Cstride) {
  __shared__ ushort_t As[128 * 64];
  __shared__ ushort_t Bs[128 * 64];
  const int tid = threadIdx.x;
  const int wid = tid >> 6, lane = tid & 63;
  const int wr = wid >> 1, wc = wid & 1;
  const int tileM = blockIdx.x * 128, tileN = blockIdx.y * 128;

  f32x4 acc[4][4];
#pragma unroll
  for (int m = 0; m < 4; ++m)
#pragma unroll
    for (int n = 0; n < 4; ++n) acc[m][n] = (f32x4){0.f, 0.f, 0.f, 0.f};

  const int srow = lane >> 3;
  const int scol = (lane & 7) * 8;

  for (int kt = 0; kt < K; kt += 64) {
    __syncthreads();
#pragma unroll
    for (int j = 0; j < 4; ++j) {
      int s = wid * 4 + j;
      const ushort_t* ga = A + (size_t)(tileM + s * 8 + srow) * Astride + kt + scol;
      const ushort_t* gb = Bt + (size_t)(tileN + s * 8 + srow) * Bstride + kt + scol;
      async16(ga, As + s * 512);
      async16(gb, Bs + s * 512);
    }
    __syncthreads();
#pragma unroll
    for (int kc = 0; kc < 2; ++kc) {
      bf16x8 af[4], bfr[4];
#pragma unroll
      for (int m = 0; m < 4; ++m)
        af[m] = *(const bf16x8*)&As[(wr * 64 + m * 16 + (lane & 15)) * 64 + kc * 32 + (lane >> 4) * 8];
#pragma unroll
      for (int n = 0; n < 4; ++n)
        bfr[n] = *(const bf16x8*)&Bs[(wc * 64 + n * 16 + (lane & 15)) * 64 + kc * 32 + (lane >> 4) * 8];
#pragma unroll
      for (int m = 0; m < 4; ++m)
#pragma unroll
        for (int n = 0; n < 4; ++n)
          acc[m][n] = __builtin_amdgcn_mfma_f32_16x16x32_bf16(af[m], bfr[n], acc[m][n], 0, 0, 0);
    }
  }

  const int r0 = tileM + wr * 64;
  const int c0 = tileN + wc * 64;
  const int rl2 = (lane >> 4) * 4;
  const int cl = lane & 15;
#pragma unroll
  for (int m = 0; m < 4; ++m)
#pragma unroll
    for (int n = 0; n < 4; ++n) {
      int col = c0 + n * 16 + cl;
#pragma unroll
      for (int r = 0; r < 4; ++r)
        Cb[(size_t)(r0 + m * 16 + rl2 + r) * Cstride + col] = f2bf(acc[m][n][r]);
    }
}

// ---------------- q-proj: qb[65536][512] = bf16(x) @ Wt^T, fused cast -------
// Block: 128 rows x full N=512, 512 threads (8 waves, 2Mx4N), BK=32, dbuf.
// A staged f32->bf16 via regs (issue-early/write-late); B via global_load_lds.
__global__ __launch_bounds__(512, 2) void gemm_qproj(
    const float* __restrict__ x, const ushort_t* __restrict__ Wt,
    ushort_t* __restrict__ qb) {
  __shared__ ushort_t As[2][128 * 32];   // 2 x 8 KB
  __shared__ ushort_t Bs[2][512 * 32];   // 2 x 32 KB
  const int tid = threadIdx.x;
  const int wid = tid >> 6, lane = tid & 63;
  const int wr = wid & 1, wc = wid >> 1;
  const int rl = lane & 15, kh = (lane >> 4) * 8;
  const int tileM = blockIdx.x * 128;

  f32x4 acc[4][8];
#pragma unroll
  for (int m = 0; m < 4; ++m)
#pragma unroll
    for (int n = 0; n < 8; ++n) acc[m][n] = (f32x4){0.f, 0.f, 0.f, 0.f};

  const int arow = tid >> 3;      // 0..63 (pair partner +64)
  const int ac4 = tid & 7;        // float4 index within 32-col slice
  const float4* x4 = (const float4*)x;
  float4 pa0, pa1;

#define QP_ISSUE_A(KT)                                                        \
  {                                                                           \
    size_t base = (size_t)(tileM + arow) * 80 + ((KT) >> 2) + ac4;            \
    pa0 = x4[base];                                                           \
    pa1 = x4[base + (size_t)64 * 80];                                         \
  }
#define QP_WRITE_A(BUF)                                                       \
  {                                                                           \
    ushort4 u0, u1;                                                           \
    u0.x = f2bf(pa0.x); u0.y = f2bf(pa0.y); u0.z = f2bf(pa0.z); u0.w = f2bf(pa0.w); \
    u1.x = f2bf(pa1.x); u1.y = f2bf(pa1.y); u1.z = f2bf(pa1.z); u1.w = f2bf(pa1.w); \
    *(ushort4*)&As[BUF][arow * 32 + ac4 * 4] = u0;                            \
    *(ushort4*)&As[BUF][(arow + 64) * 32 + ac4 * 4] = u1;                     \
  }
#define QP_STAGE_B(BUF, KT)                                                   \
  _Pragma("unroll")                                                           \
  for (int i = 0; i < 4; ++i) {                                               \
    int chunk = tid + i * 512;                                                \
    int n = chunk >> 2, c8 = chunk & 3;                                       \
    async16(Wt + (size_t)n * QDIM + (KT) + c8 * 8, &Bs[BUF][chunk * 8]);      \
  }

  QP_ISSUE_A(0)
  QP_WRITE_A(0)
  QP_STAGE_B(0, 0)
  __syncthreads();

  for (int s = 0; s < 10; ++s) {
    const int cur = s & 1;
    if (s < 9) {
      QP_ISSUE_A((s + 1) * 32)
      QP_STAGE_B(cur ^ 1, (s + 1) * 32)
    }
    bf16x8 af[4], bfr[8];
#pragma unroll
    for (int m = 0; m < 4; ++m)
      af[m] = *(const bf16x8*)&As[cur][(wr * 64 + m * 16 + rl) * 32 + kh];
#pragma unroll
    for (int n = 0; n < 8; ++n)
      bfr[n] = *(const bf16x8*)&Bs[cur][(wc * 128 + n * 16 + rl) * 32 + kh];
#pragma unroll
    for (int m = 0; m < 4; ++m)
#pragma unroll
      for (int n = 0; n < 8; ++n)
        acc[m][n] = __builtin_amdgcn_mfma_f32_16x16x32_bf16(af[m], bfr[n], acc[m][n], 0, 0, 0);
    if (s < 9) QP_WRITE_A(cur ^ 1)
    __syncthreads();
  }

  const int r0 = tileM + wr * 64;
  const int c0 = wc * 128;
  const int rl2 = (lane >> 4) * 4, cl = lane & 15;
#pragma unroll
  for (int m = 0; m < 4; ++m)
#pragma unroll
    for (int n = 0; n < 8; ++n)
#pragma unroll
      for (int r = 0; r < 4; ++r)
        qb[(size_t)(r0 + m * 16 + rl2 + r) * INNER + c0 + n * 16 + cl] = f2bf(acc[m][n][r]);
}

// ---------------- out-proj: out[65536][320] = ab @ Wt^T + bo (f32) ---------
// Block: 128 rows x full N=384(pad), 512 threads (8 waves, 2Mx4N), BK=64, dbuf.
__global__ __launch_bounds__(512, 2) void gemm_oproj(
    const ushort_t* __restrict__ A, const ushort_t* __restrict__ Wt,
    const float* __restrict__ bo, float* __restrict__ out) {
  __shared__ ushort_t As[2][128 * 64];   // 2 x 16 KB
  __shared__ ushort_t Bs[2][384 * 64];   // 2 x 48 KB
  const int tid = threadIdx.x;
  const int wid = tid >> 6, lane = tid & 63;
  const int wr = wid & 1, wc = wid >> 1;
  const int rl = lane & 15, kh = (lane >> 4) * 8;
  const int tileM = blockIdx.x * 128;

  f32x4 acc[4][6];
#pragma unroll
  for (int m = 0; m < 4; ++m)
#pragma unroll
    for (int n = 0; n < 6; ++n) acc[m][n] = (f32x4){0.f, 0.f, 0.f, 0.f};

#define OP_STAGE(BUF, KT)                                                     \
  _Pragma("unroll")                                                           \
  for (int i = 0; i < 2; ++i) {                                               \
    int chunk = tid + i * 512;                                                \
    int row = chunk >> 3, c8 = chunk & 7;                                     \
    async16(A + (size_t)(tileM + row) * INNER + (KT) + c8 * 8,                \
            &As[BUF][chunk * 8]);                                             \
  }                                                                           \
  _Pragma("unroll")                                                           \
  for (int i = 0; i < 6; ++i) {                                               \
    int chunk = tid + i * 512;                                                \
    int n = chunk >> 3, c8 = chunk & 7;                                       \
    async16(Wt + (size_t)n * INNER + (KT) + c8 * 8, &Bs[BUF][chunk * 8]);     \
  }

  OP_STAGE(0, 0)
  __syncthreads();

  for (int s = 0; s < 8; ++s) {
    const int cur = s & 1;
    if (s < 7) { OP_STAGE(cur ^ 1, (s + 1) * 64) }
#pragma unroll
    for (int kc = 0; kc < 2; ++kc) {
      bf16x8 af[4], bfr[6];
#pragma unroll
      for (int m = 0; m < 4; ++m)
        af[m] = *(const bf16x8*)&As[cur][(wr * 64 + m * 16 + rl) * 64 + kc * 32 + kh];
#pragma unroll
      for (int n = 0; n < 6; ++n)
        bfr[n] = *(const bf16x8*)&Bs[cur][(wc * 96 + n * 16 + rl) * 64 + kc * 32 + kh];
#pragma unroll
      for (int m = 0; m < 4; ++m)
#pragma unroll
        for (int n = 0; n < 6; ++n)
          acc[m][n] = __builtin_amdgcn_mfma_f32_16x16x32_bf16(af[m], bfr[n], acc[m][n], 0, 0, 0);
    }
    __syncthreads();
  }

  const int r0 = tileM + wr * 64;
  const int c0 = wc * 96;
  const int rl2 = (lane >> 4) * 4, cl = lane & 15;
#pragma unroll
  for (int n = 0; n < 6; ++n) {
    int col = c0 + n * 16 + cl;
    if (col < QDIM) {
      float bv = bo[col];
#pragma unroll
      for (int m = 0; m < 4; ++m)
#pragma unroll
        for (int r = 0; r < 4; ++r)
          out[(size_t)(r0 + m * 16 + rl2 + r) * QDIM + col] = acc[m][n][r] + bv;
    }
  }
}

// ---------------- fused attention (unchanged from round 2) ----------------
__global__ __launch_bounds__(256) void attn_kernel(
    const ushort_t* __restrict__ qb, const ushort_t* __restrict__ kvb,
    const ushort_t* __restrict__ vt, const float* __restrict__ biasT,
    ushort_t* __restrict__ ab) {
  __shared__ ushort_t Vt[64 * VT_STR];
  __shared__ ushort_t P[4 * 16 * VT_STR];
  const int qt = blockIdx.x, h = blockIdx.y, b = blockIdx.z;
  const int tid = threadIdx.x, wid = tid >> 6, lane = tid & 63;
  const int rl = lane & 15;
  const int kh = (lane >> 4) * 8;

  const ushort_t* vtg = vt + (size_t)(b * HEADS + h) * (64 * VT_STR);
  for (int i = tid; i < 832; i += 256) async16(vtg + i * 8, Vt + i * 8);
  for (int i = tid; i < 832; i += 256)
    *(bf16x8*)&P[i * 8] = (bf16x8){0, 0, 0, 0, 0, 0, 0, 0};

  bf16x8 kf[5][2];
  float bias_v[5];
#pragma unroll
  for (int nt = 0; nt < 5; ++nt) {
    int kv = nt * 16 + rl;
    bias_v[nt] = biasT[b * 80 + kv];
    kf[nt][0] = (bf16x8){0, 0, 0, 0, 0, 0, 0, 0};
    kf[nt][1] = (bf16x8){0, 0, 0, 0, 0, 0, 0, 0};
    if (kv < NKV) {
      const ushort_t* kp = &kvb[(size_t)(b * NKV + kv) * 1024 + h * 64 + kh];
      kf[nt][0] = *(const bf16x8*)kp;
      kf[nt][1] = *(const bf16x8*)(kp + 32);
    }
  }
  __syncthreads();

  const int qbase = b * NQ + qt * 256;
  const int pbase = wid * (16 * VT_STR);
#pragma unroll 1
  for (int chunk = 0; chunk < 4; ++chunk) {
    if (chunk) __syncthreads();
    const int row0 = chunk * 64 + wid * 16;

    const ushort_t* qp = &qb[(size_t)(qbase + row0 + rl) * INNER + h * 64 + kh];
    bf16x8 qf0 = *(const bf16x8*)qp;
    bf16x8 qf1 = *(const bf16x8*)(qp + 32);

    f32x4 s[5];
#pragma unroll
    for (int nt = 0; nt < 5; ++nt) {
      s[nt] = (f32x4){0.f, 0.f, 0.f, 0.f};
      s[nt] = __builtin_amdgcn_mfma_f32_16x16x32_bf16(qf0, kf[nt][0], s[nt], 0, 0, 0);
      s[nt] = __builtin_amdgcn_mfma_f32_16x16x32_bf16(qf1, kf[nt][1], s[nt], 0, 0, 0);
    }

    float mx[4] = {-3.0e38f, -3.0e38f, -3.0e38f, -3.0e38f};
#pragma unroll
    for (int nt = 0; nt < 5; ++nt)
#pragma unroll
      for (int r = 0; r < 4; ++r) {
        float v = s[nt][r] + bias_v[nt];
        s[nt][r] = v;
        mx[r] = fmaxf(mx[r], v);
      }
#pragma unroll
    for (int d = 1; d < 16; d <<= 1)
#pragma unroll
      for (int r = 0; r < 4; ++r) mx[r] = fmaxf(mx[r], __shfl_xor(mx[r], d, 64));

    float sm[4] = {0.f, 0.f, 0.f, 0.f};
#pragma unroll
    for (int nt = 0; nt < 5; ++nt)
#pragma unroll
      for (int r = 0; r < 4; ++r) {
        float p = __expf(s[nt][r] - mx[r]);
        s[nt][r] = p;
        sm[r] += p;
      }
#pragma unroll
    for (int d = 1; d < 16; d <<= 1)
#pragma unroll
      for (int r = 0; r < 4; ++r) sm[r] += __shfl_xor(sm[r], d, 64);

    float rcp[4];
#pragma unroll
    for (int r = 0; r < 4; ++r) rcp[r] = 1.0f / sm[r];

#pragma unroll
    for (int nt = 0; nt < 5; ++nt)
#pragma unroll
      for (int r = 0; r < 4; ++r)
        P[pbase + ((lane >> 4) * 4 + r) * VT_STR + nt * 16 + rl] = f2bf(s[nt][r]);

    f32x4 o[4];
#pragma unroll
    for (int n = 0; n < 4; ++n) o[n] = (f32x4){0.f, 0.f, 0.f, 0.f};
#pragma unroll
    for (int kc = 0; kc < 3; ++kc) {
      bf16x8 pf = *(const bf16x8*)&P[pbase + rl * VT_STR + kc * 32 + kh];
#pragma unroll
      for (int n = 0; n < 4; ++n) {
        bf16x8 vf = *(const bf16x8*)&Vt[(n * 16 + rl) * VT_STR + kc * 32 + kh];
        o[n] = __builtin_amdgcn_mfma_f32_16x16x32_bf16(pf, vf, o[n], 0, 0, 0);
      }
    }

#pragma unroll
    for (int n = 0; n < 4; ++n)
#pragma unroll
      for (int r = 0; r < 4; ++r)
        P[pbase + ((lane >> 4) * 4 + r) * VT_STR + n * 16 + rl] = f2bf(o[n][r] * rcp[r]);

    __syncthreads();

    {
      const int rflat = tid >> 2, d0 = (tid & 3) * 16;
      const ushort_t* src = &P[(rflat >> 4) * (16 * VT_STR) + (rflat & 15) * VT_STR + d0];
      ushort_t* dst = &ab[(size_t)(qbase + chunk * 64 + rflat) * INNER + h * 64 + d0];
      *(bf16x8*)dst = *(const bf16x8*)src;
      *(bf16x8*)(dst + 8) = *(const bf16x8*)(src + 8);
    }
  }
}

// ---------------- host ----------------
extern "C" void kernel_launch(void* const* d_in, const int* in_sizes, int n_in,
                              void* d_out, int out_size, void* d_ws, size_t ws_size,
                              hipStream_t stream) {
  (void)in_sizes; (void)n_in; (void)out_size; (void)ws_size;
  const float* x   = (const float*)d_in[0];
  const float* ctx = (const float*)d_in[1];
  const unsigned char* mask = (const unsigned char*)d_in[2];
  const float* Wq = (const float*)d_in[3];
  const float* Wk = (const float*)d_in[4];
  const float* Wv = (const float*)d_in[5];
  const float* Wo = (const float*)d_in[6];
  const float* bo = (const float*)d_in[7];
  float* out = (float*)d_out;

  char* ws = (char*)d_ws;
  size_t off = 0;
  auto alloc = [&](size_t bytes) {
    char* p = ws + off;
    off += (bytes + 255) & ~(size_t)255;
    return p;
  };
  float*    biasT = (float*)alloc(B_SZ * 80 * sizeof(float));
  ushort_t* ab    = (ushort_t*)alloc((size_t)M_ROWS * INNER * 2);   // [65536][512]
  ushort_t* qb    = (ushort_t*)alloc((size_t)M_ROWS * INNER * 2);   // [65536][512]
  ushort_t* cb    = (ushort_t*)alloc((size_t)1280 * CDIM * 2);      // ctx bf16 padded
  ushort_t* Wqb   = (ushort_t*)alloc((size_t)INNER * QDIM * 2);     // (0.125*Wq)^T [512][320]
  ushort_t* Wkvb  = (ushort_t*)alloc((size_t)1024 * CDIM * 2);      // [[Wk^T];[Wv^T]]
  ushort_t* Wob   = (ushort_t*)alloc((size_t)384 * INNER * 2);      // Wo^T pad [384][512]
  ushort_t* kvb   = (ushort_t*)alloc((size_t)1280 * 1024 * 2);      // [1280][1024]
  ushort_t* vt    = (ushort_t*)alloc((size_t)B_SZ * HEADS * 64 * VT_STR * 2);

  mask_bias_kernel<<<1, 256, 0, stream>>>(mask, biasT);
  cast_f32_bf16<<<512, 256, 0, stream>>>(ctx, cb, B_SZ * NKV * CDIM / 4);
  tcast_f32_bf16<<<640, 256, 0, stream>>>(Wq, Wqb, QDIM, INNER, INNER, 0.125f);
  tcast_f32_bf16<<<1536, 256, 0, stream>>>(Wk, Wkvb, CDIM, INNER, INNER, 1.0f);
  tcast_f32_bf16<<<1536, 256, 0, stream>>>(Wv, Wkvb + (size_t)INNER * CDIM, CDIM, INNER, INNER, 1.0f);
  tcast_f32_bf16<<<768, 256, 0, stream>>>(Wo, Wob, INNER, QDIM, 384, 1.0f);

  // q = bf16(x) @ (0.125*Wq) — cast fused, A read exactly once
  gemm_qproj<<<M_ROWS / 128, 512, 0, stream>>>(x, Wqb, qb);
  // [k|v] = ctx @ [Wk|Wv]
  dim3 g2(1280 / 128, 1024 / 128);
  gemm_bf16<<<g2, 256, 0, stream>>>(cb, Wkvb, kvb, CDIM, CDIM, CDIM, 1024);
  // V -> vt[b][h][d][104]
  vtrans_kernel<<<dim3(16, HEADS, B_SZ), 256, 0, stream>>>(kvb, vt);
  // attention
  attn_kernel<<<dim3(NQ / 256, HEADS, B_SZ), 256, 0, stream>>>(qb, kvb, vt, biasT, ab);
  // out = ab @ Wo + bo — A read exactly once, f32 epilogue
  gemm_oproj<<<M_ROWS / 128, 512, 0, stream>>>(ab, Wob, bo, out);
}